// Round 4
// baseline (199.807 us; speedup 1.0000x reference)
//
#include <hip/hip_runtime.h>

// HetConv via bf16 MFMA implicit GEMM, v4.
//  - Part A: dense 256x256 pointwise GEMM (W_hat = center tap or W1)
//  - Part B: grouped (j%4==oc%4) 8 non-center taps, block-diagonal in permuted channels
//  - Weights prepacked (prepass) -> staged chunk-wise into LDS via straight 16B copies.
//  - 512 threads (8 waves, 2 mrow x 4 ncol), M=256 oc x N=256 px (4 output rows) per block.
//  - T14 pipeline: issue global loads for chunk h+1 BEFORE compute(h); after compute,
//    barrier -> ds_write -> barrier. Weights never feed MFMA from global (round-3 lesson).

#define IN_C  256
#define OUT_C 256
#define HH    64
#define WW    64

typedef __attribute__((ext_vector_type(8))) short bf16x8;
typedef __attribute__((ext_vector_type(4))) short bf16x4;
typedef __attribute__((ext_vector_type(4))) float f32x4;

__device__ __forceinline__ unsigned short f2bf(float f) {
    union { float f; unsigned int u; } v; v.f = f;
    unsigned int r = (v.u + 0x7FFFu + ((v.u >> 16) & 1u)) >> 16;
    return (unsigned short)r;
}

// ---------------- weight prepass ----------------
// AH: [h(8)][p(256)][kc(4)][e(8)]  (65536 elems)
// AK: offset 65536: [h(8)][tf(8)][lo(64)][kc(4)][e(8)] (131072 elems)
//   h = h2*4+g ; i = kc*8+e ; j = g + 4*(32*h2 + i) ; tap_full = tf<4 ? tf : tf+1
__global__ __launch_bounds__(256)
void hetconv_prep(const float* __restrict__ Wk, const float* __restrict__ W1,
                  unsigned short* __restrict__ ws16) {
    const int TOTAL = 65536 + 131072;
    for (int idx = blockIdx.x * 256 + threadIdx.x; idx < TOTAL; idx += gridDim.x * 256) {
        float f;
        if (idx < 65536) {
            int e = idx & 7, kc = (idx >> 3) & 3, p = (idx >> 5) & 255, h = idx >> 13;
            int g = h & 3, h2 = h >> 2;
            int i = kc * 8 + e;
            int j = g + 4 * (32 * h2 + i);
            int oc = 4 * (p & 63) + (p >> 6);
            f = ((p >> 6) == g) ? Wk[(oc * IN_C + j) * 9 + 4] : W1[oc * IN_C + j];
        } else {
            int k = idx - 65536;
            int e = k & 7, kc = (k >> 3) & 3, lo = (k >> 5) & 63, tf = (k >> 11) & 7, h = k >> 14;
            int g = h & 3, h2 = h >> 2;
            int i = kc * 8 + e;
            int j = g + 4 * (32 * h2 + i);
            int oc = 4 * lo + g;
            int tfull = tf < 4 ? tf : tf + 1;
            f = Wk[(oc * IN_C + j) * 9 + tfull];
        }
        ws16[idx] = f2bf(f);
    }
}

// ---------------- main kernel helpers ----------------
#define XSPAD 36
#define XROWS 6
#define XSSZ  (XROWS * 66 * XSPAD)   // 14256 elems per buffer (28512 B)

// x chunk: 32 ic x 6 rows x 64 cols. tasks [r(6)][q(16)][icp(16)] = 1536 = 512*3
__device__ __forceinline__ void stage_x_loads(const float* __restrict__ x, int n, int y0,
                                              int ck, int t, float4 v[3][2]) {
    const int g = ck & 3, h2 = ck >> 2;
    #pragma unroll
    for (int it = 0; it < 3; ++it) {
        int tau = t + it * 512;
        int icp = tau & 15, q = (tau >> 4) & 15, r = tau >> 8;   // r 0..5
        int j0 = g + 4 * (32 * h2 + 2 * icp);
        int gy = y0 + r - 1;
        float4 z = {0.f, 0.f, 0.f, 0.f};
        v[it][0] = z; v[it][1] = z;
        if ((unsigned)gy < 64u) {
            const float* p0 = x + (((size_t)n * IN_C + j0) << 12) + (gy << 6) + (q << 2);
            v[it][0] = *(const float4*)p0;
            v[it][1] = *(const float4*)(p0 + 16384);   // plane j0+4
        }
    }
}

__device__ __forceinline__ void stage_x_writes(int t, float4 v[3][2], unsigned short* __restrict__ xb) {
    #pragma unroll
    for (int it = 0; it < 3; ++it) {
        int tau = t + it * 512;
        int icp = tau & 15, q = (tau >> 4) & 15, r = tau >> 8;
        unsigned d0 = (unsigned)f2bf(v[it][0].x) | ((unsigned)f2bf(v[it][1].x) << 16);
        unsigned d1 = (unsigned)f2bf(v[it][0].y) | ((unsigned)f2bf(v[it][1].y) << 16);
        unsigned d2 = (unsigned)f2bf(v[it][0].z) | ((unsigned)f2bf(v[it][1].z) << 16);
        unsigned d3 = (unsigned)f2bf(v[it][0].w) | ((unsigned)f2bf(v[it][1].w) << 16);
        int rb = (r * 66 + q * 4 + 1) * XSPAD + 2 * icp;
        *(unsigned*)&xb[rb]             = d0;
        *(unsigned*)&xb[rb + XSPAD]     = d1;
        *(unsigned*)&xb[rb + 2 * XSPAD] = d2;
        *(unsigned*)&xb[rb + 3 * XSPAD] = d3;
    }
}

// weights: wh 8192 el (2 frags/thread), wk 16384 el (4 frags/thread)
__device__ __forceinline__ void stage_w_loads(const unsigned short* __restrict__ wgt,
                                              int ck, int t, bf16x8 wv[6]) {
    const unsigned short* AHh = wgt + ck * 8192;
    const unsigned short* AKh = wgt + 65536 + ck * 16384;
    wv[0] = *(const bf16x8*)&AHh[t * 8];
    wv[1] = *(const bf16x8*)&AHh[(t + 512) * 8];
    #pragma unroll
    for (int it = 0; it < 4; ++it)
        wv[2 + it] = *(const bf16x8*)&AKh[(t + it * 512) * 8];
}

__device__ __forceinline__ void stage_w_writes(int t, bf16x8 wv[6],
                                               unsigned short* __restrict__ wh,
                                               unsigned short* __restrict__ wk) {
    *(bf16x8*)&wh[t * 8]           = wv[0];
    *(bf16x8*)&wh[(t + 512) * 8]   = wv[1];
    #pragma unroll
    for (int it = 0; it < 4; ++it)
        *(bf16x8*)&wk[(t + it * 512) * 8] = wv[2 + it];
}

__device__ __forceinline__ bf16x8 lds_bfrag(const unsigned short* __restrict__ xb, int off) {
    bf16x4 lo = *(const bf16x4*)&xb[off];
    bf16x4 hi = *(const bf16x4*)&xb[off + 4];
    return __builtin_shufflevector(lo, hi, 0, 1, 2, 3, 4, 5, 6, 7);
}

template <int G>
__device__ __forceinline__ void compute_chunk(const unsigned short* __restrict__ xb,
        const unsigned short* __restrict__ wh, const unsigned short* __restrict__ wk,
        f32x4 acc[8][4], int mrow, int ncol, int lrow, int kc) {
    // ---- part A: dense pointwise, K=32 ----
    bf16x8 bfr[4];
    #pragma unroll
    for (int ni = 0; ni < 4; ++ni)
        bfr[ni] = lds_bfrag(xb, ((ncol + 1) * 66 + ni * 16 + lrow + 1) * XSPAD + kc * 8);
    #pragma unroll
    for (int mi = 0; mi < 8; ++mi) {
        int m = mrow + 2 * mi;
        bf16x8 a = *(const bf16x8*)&wh[(m * 16 + lrow) * 32 + kc * 8];
        #pragma unroll
        for (int ni = 0; ni < 4; ++ni)
            acc[mi][ni] = __builtin_amdgcn_mfma_f32_16x16x32_bf16(a, bfr[ni], acc[mi][ni], 0, 0, 0);
    }
    // ---- part B: 8 non-center taps, group G ----
    #pragma unroll
    for (int tf = 0; tf < 8; ++tf) {
        const int tfull = tf < 4 ? tf : tf + 1;
        const int dy = tfull / 3 - 1, dx = tfull % 3 - 1;
        const unsigned short* ak = &wk[((tf * 64 + mrow * 16 + lrow) * 4 + kc) * 8];
        bf16x8 a0 = *(const bf16x8*)ak;
        bf16x8 a1 = *(const bf16x8*)(ak + 1024);   // rows +32 (m = mrow+2)
        #pragma unroll
        for (int ni = 0; ni < 4; ++ni) {
            bf16x8 bb = lds_bfrag(xb, ((ncol + 1 + dy) * 66 + ni * 16 + lrow + 1 + dx) * XSPAD + kc * 8);
            acc[2 * G + 0][ni] = __builtin_amdgcn_mfma_f32_16x16x32_bf16(a0, bb, acc[2 * G + 0][ni], 0, 0, 0);
            acc[2 * G + 1][ni] = __builtin_amdgcn_mfma_f32_16x16x32_bf16(a1, bb, acc[2 * G + 1][ni], 0, 0, 0);
        }
    }
}

// ---------------- main MFMA kernel ----------------
// 512 threads = 8 waves (2 mrow x 4 ncol). Block: M=256 oc x 4 output rows x 64 cols.
__global__ __launch_bounds__(512, 2)
void hetconv_mfma(const float* __restrict__ x,
                  const unsigned short* __restrict__ wgt,
                  float* __restrict__ out) {
    __shared__ __align__(16) unsigned short xs[2][XSSZ];     // 57024 B
    __shared__ __align__(16) unsigned short whs[256 * 32];   // 16384 B
    __shared__ __align__(16) unsigned short wks[8 * 64 * 32];// 32768 B

    const int t    = threadIdx.x;
    const int l    = t & 63;
    const int w    = t >> 6;
    const int mrow = w & 1;
    const int ncol = w >> 1;      // output row within tile, 0..3
    const int lrow = l & 15;
    const int kc   = l >> 4;

    const int bid = blockIdx.x;                 // 512 blocks
    const int n   = (bid & 7) * 4 + (bid >> 7); // XCD-major n
    const int y0  = ((bid >> 3) & 15) * 4;

    f32x4 acc[8][4];
    #pragma unroll
    for (int mi = 0; mi < 8; ++mi)
        #pragma unroll
        for (int ni = 0; ni < 4; ++ni) acc[mi][ni] = (f32x4){0.f, 0.f, 0.f, 0.f};

    // ---- prologue: stage chunk 0 + zero halo cols of both buffers ----
    {
        float4 xv[3][2];
        bf16x8 wv[6];
        stage_x_loads(x, n, y0, 0, t, xv);
        stage_w_loads(wgt, 0, t, wv);
        if (t < 384) {   // 2 buf x 6 r x 2 side x 16 dwords
            int buf = t & 1, rem = t >> 1;
            int r = rem >> 5, side = (rem >> 4) & 1, u = rem & 15;
            *(unsigned*)&xs[buf][(r * 66 + side * 65) * XSPAD + u * 2] = 0u;
        }
        stage_x_writes(t, xv, xs[0]);
        stage_w_writes(t, wv, whs, wks);
        __syncthreads();
    }

    // ---- main loop: 8 chunks, loads(h+1) -> compute(h) -> bar -> writes -> bar ----
    #pragma unroll 1
    for (int h2 = 0; h2 < 2; ++h2) {
#define BODY(G)                                                                   \
        {                                                                         \
            const int ck = h2 * 4 + G;                                            \
            float4 xv[3][2];                                                      \
            bf16x8 wv[6];                                                         \
            if (G < 3 || h2 == 0) {                                               \
                stage_x_loads(x, n, y0, ck + 1, t, xv);                           \
                stage_w_loads(wgt, ck + 1, t, wv);                                \
            }                                                                     \
            compute_chunk<G>(xs[ck & 1], whs, wks, acc, mrow, ncol, lrow, kc);    \
            if (G < 3 || h2 == 0) {                                               \
                __syncthreads();                                                  \
                stage_x_writes(t, xv, xs[(ck + 1) & 1]);                          \
                stage_w_writes(t, wv, whs, wks);                                  \
                __syncthreads();                                                  \
            }                                                                     \
        }
        BODY(0) BODY(1) BODY(2) BODY(3)
#undef BODY
    }

    // ---- epilogue: C/D layout col=lane&15, row=(lane>>4)*4+reg ----
    #pragma unroll
    for (int mi = 0; mi < 8; ++mi) {
        int m = mrow + 2 * mi;
        #pragma unroll
        for (int ni = 0; ni < 4; ++ni) {
            #pragma unroll
            for (int reg = 0; reg < 4; ++reg) {
                int p  = m * 16 + kc * 4 + reg;
                int oc = 4 * (p & 63) + (p >> 6);
                out[(((size_t)n * OUT_C + oc) * HH + (y0 + ncol)) * WW + ni * 16 + lrow] = acc[mi][ni][reg];
            }
        }
    }
}

// ---------------- fp32 fallback (only if ws too small) ----------------
#define TH 16
#define TW 16
#define ICC 16
__global__ __launch_bounds__(256)
void hetconv_fp32(const float* __restrict__ x,
                  const float* __restrict__ Wk,
                  const float* __restrict__ W1,
                  float* __restrict__ out) {
    const int t    = threadIdx.x;
    const int g    = blockIdx.y;
    const int n    = blockIdx.z;
    const int tile = blockIdx.x;
    const int ty0  = (tile >> 2) * TH;
    const int tx0  = (tile & 3) * TW;
    const int ol = t & 7;
    const int pl = t >> 3;
    const int r  = pl >> 1;
    const int ch = (pl & 1) * 8;
    __shared__ __align__(16) float xsf[ICC * 18 * 20];
    __shared__ __align__(16) float w1s[ICC * 64];
    __shared__ __align__(16) float wksf[4 * 9 * 64];
    float acc[8][8];
    #pragma unroll
    for (int k = 0; k < 8; ++k)
        #pragma unroll
        for (int p = 0; p < 8; ++p) acc[k][p] = 0.f;
    for (int ic0 = 0; ic0 < IN_C; ic0 += ICC) {
        for (int idx = t; idx < ICC * 18 * 18; idx += 256) {
            int ic = idx / 324, rem = idx - ic * 324, rr = rem / 18, cc = rem - rr * 18;
            int gy = ty0 + rr - 1, gx = tx0 + cc - 1;
            float v = 0.f;
            if (gy >= 0 && gy < HH && gx >= 0 && gx < WW)
                v = x[(((size_t)n * IN_C + ic0 + ic) * HH + gy) * WW + gx];
            xsf[ic * 360 + rr * 20 + cc] = v;
        }
        for (int idx = t; idx < ICC * 64; idx += 256) {
            int ic = idx >> 6, o = idx & 63;
            w1s[idx] = W1[(g + 4 * o) * IN_C + ic0 + ic];
        }
        for (int idx = t; idx < 4 * 9 * 64; idx += 256) {
            int a = idx / 576, rem = idx - a * 576, tap = rem >> 6, o = rem & 63;
            wksf[idx] = Wk[((g + 4 * o) * IN_C + ic0 + g + 4 * a) * 9 + tap];
        }
        __syncthreads();
        for (int ic = 0; ic < ICC; ++ic) {
            if ((ic & 3) != g) {
                const float* rowp = &xsf[ic * 360 + (r + 1) * 20 + ch];
                float4 A = *(const float4*)rowp;
                float4 B = *(const float4*)(rowp + 4);
                float  c8 = rowp[8];
                float xv[8] = {A.y, A.z, A.w, B.x, B.y, B.z, B.w, c8};
                const float* wp = &w1s[ic * 64 + ol * 8];
                float4 wA = *(const float4*)wp;
                float4 wB = *(const float4*)(wp + 4);
                float wv[8] = {wA.x, wA.y, wA.z, wA.w, wB.x, wB.y, wB.z, wB.w};
                #pragma unroll
                for (int k = 0; k < 8; ++k)
                    #pragma unroll
                    for (int p = 0; p < 8; ++p) acc[k][p] += wv[k] * xv[p];
            } else {
                const int a = ic >> 2;
                #pragma unroll
                for (int dy = -1; dy <= 1; ++dy) {
                    const float* rowp = &xsf[ic * 360 + (r + 1 + dy) * 20 + ch];
                    float4 A = *(const float4*)rowp;
                    float4 B = *(const float4*)(rowp + 4);
                    float2 C = *(const float2*)(rowp + 8);
                    float seg[10] = {A.x, A.y, A.z, A.w, B.x, B.y, B.z, B.w, C.x, C.y};
                    #pragma unroll
                    for (int dxi = 0; dxi < 3; ++dxi) {
                        const float* wp = &wksf[(a * 9 + (dy + 1) * 3 + dxi) * 64 + ol * 8];
                        float4 wA = *(const float4*)wp;
                        float4 wB = *(const float4*)(wp + 4);
                        float wv[8] = {wA.x, wA.y, wA.z, wA.w, wB.x, wB.y, wB.z, wB.w};
                        #pragma unroll
                        for (int k = 0; k < 8; ++k)
                            #pragma unroll
                            for (int p = 0; p < 8; ++p) acc[k][p] += wv[k] * seg[p + dxi];
                    }
                }
            }
        }
        __syncthreads();
    }
    #pragma unroll
    for (int k = 0; k < 8; ++k) {
        int oc = g + 4 * (ol * 8 + k);
        size_t base = (((size_t)n * OUT_C + oc) * HH + (ty0 + r)) * WW + tx0 + ch;
        float4 v0 = {acc[k][0], acc[k][1], acc[k][2], acc[k][3]};
        float4 v1 = {acc[k][4], acc[k][5], acc[k][6], acc[k][7]};
        *(float4*)(&out[base])     = v0;
        *(float4*)(&out[base + 4]) = v1;
    }
}

extern "C" void kernel_launch(void* const* d_in, const int* in_sizes, int n_in,
                              void* d_out, int out_size, void* d_ws, size_t ws_size,
                              hipStream_t stream) {
    const float* x  = (const float*)d_in[0];
    const float* Wk = (const float*)d_in[1];
    const float* W1 = (const float*)d_in[2];
    float* outp = (float*)d_out;

    if (ws_size >= (size_t)(65536 + 131072) * sizeof(unsigned short)) {
        hetconv_prep<<<256, 256, 0, stream>>>(Wk, W1, (unsigned short*)d_ws);
        hetconv_mfma<<<512, 512, 0, stream>>>(x, (const unsigned short*)d_ws, outp);
    } else {
        hetconv_fp32<<<dim3(16, 4, 32), 256, 0, stream>>>(x, Wk, W1, outp);
    }
}

// Round 5
// 173.333 us; speedup vs baseline: 1.1527x; 1.1527x over previous
//
#include <hip/hip_runtime.h>

// HetConv via bf16 MFMA implicit GEMM, v5 = round-2 structure + staging overhaul.
//  - Part A: dense 256x256 pointwise GEMM (W_hat = center tap or W1), permuted channels
//  - Part B: grouped (j%4==oc%4) 8 non-center taps, block-diagonal in permuted channels
//  - Weights: prepacked fragment-major in d_ws; staged per chunk via global_load_lds
//    width=16 (linear both sides -> DMA-legal), no VGPR round trip, no ds_writes.
//  - x: global->VGPR loads issued BEFORE compute (T14), cvt fp32->bf16 under compute,
//    ds_write in a short post-barrier phase. 2 barriers per chunk.
//  - LDS 67 KB -> 2 blocks/CU (the round-3/4 regressions both lost this).

#define IN_C  256
#define OUT_C 256
#define HH    64
#define WW    64

typedef __attribute__((ext_vector_type(8))) short bf16x8;
typedef __attribute__((ext_vector_type(4))) short bf16x4;
typedef __attribute__((ext_vector_type(4))) float f32x4;

__device__ __forceinline__ unsigned short f2bf(float f) {
    union { float f; unsigned int u; } v; v.f = f;
    unsigned int r = (v.u + 0x7FFFu + ((v.u >> 16) & 1u)) >> 16;
    return (unsigned short)r;
}

// ---------------- weight prepass (fragment-major; identical to v4) ----------------
// AH: [h(8)][p(256)][kc(4)][e(8)]  (65536 elems)
// AK: offset 65536: [h(8)][tf(8)][lo(64)][kc(4)][e(8)] (131072 elems)
//   h = h2*4+g ; i = kc*8+e ; j = g + 4*(32*h2 + i) ; tap_full = tf<4 ? tf : tf+1
__global__ __launch_bounds__(256)
void hetconv_prep(const float* __restrict__ Wk, const float* __restrict__ W1,
                  unsigned short* __restrict__ ws16) {
    const int TOTAL = 65536 + 131072;
    for (int idx = blockIdx.x * 256 + threadIdx.x; idx < TOTAL; idx += gridDim.x * 256) {
        float f;
        if (idx < 65536) {
            int e = idx & 7, kc = (idx >> 3) & 3, p = (idx >> 5) & 255, h = idx >> 13;
            int g = h & 3, h2 = h >> 2;
            int i = kc * 8 + e;
            int j = g + 4 * (32 * h2 + i);
            int oc = 4 * (p & 63) + (p >> 6);
            f = ((p >> 6) == g) ? Wk[(oc * IN_C + j) * 9 + 4] : W1[oc * IN_C + j];
        } else {
            int k = idx - 65536;
            int e = k & 7, kc = (k >> 3) & 3, lo = (k >> 5) & 63, tf = (k >> 11) & 7, h = k >> 14;
            int g = h & 3, h2 = h >> 2;
            int i = kc * 8 + e;
            int j = g + 4 * (32 * h2 + i);
            int oc = 4 * lo + g;
            int tfull = tf < 4 ? tf : tf + 1;
            f = Wk[(oc * IN_C + j) * 9 + tfull];
        }
        ws16[idx] = f2bf(f);
    }
}

// ---------------- main kernel helpers ----------------
#define XSPAD 36
#define XSSZ  (4 * 66 * XSPAD)   // 9504 elems (19008 B)

// x chunk: 32 ic x 4 rows x 64 cols. tasks [r(4)][q(16)][icp(16)] = 1024 = 256*4
__device__ __forceinline__ void stage_x_loads(const float* __restrict__ x, int n, int y0,
                                              int ck, int t, float4 v[4][2]) {
    const int g = ck & 3, h2 = ck >> 2;
    #pragma unroll
    for (int it = 0; it < 4; ++it) {
        int tau = t + it * 256;
        int icp = tau & 15, q = (tau >> 4) & 15, r = tau >> 8;
        int j0 = g + 4 * (32 * h2 + 2 * icp);
        int gy = y0 + r - 1;
        float4 z = {0.f, 0.f, 0.f, 0.f};
        v[it][0] = z; v[it][1] = z;
        if ((unsigned)gy < 64u) {
            const float* p0 = x + (((size_t)n * IN_C + j0) << 12) + (gy << 6) + (q << 2);
            v[it][0] = *(const float4*)p0;
            v[it][1] = *(const float4*)(p0 + 16384);   // plane j0+4
        }
    }
}

__device__ __forceinline__ void stage_x_writes(int t, float4 v[4][2], unsigned short* __restrict__ xb) {
    #pragma unroll
    for (int it = 0; it < 4; ++it) {
        int tau = t + it * 256;
        int icp = tau & 15, q = (tau >> 4) & 15, r = tau >> 8;
        unsigned d0 = (unsigned)f2bf(v[it][0].x) | ((unsigned)f2bf(v[it][1].x) << 16);
        unsigned d1 = (unsigned)f2bf(v[it][0].y) | ((unsigned)f2bf(v[it][1].y) << 16);
        unsigned d2 = (unsigned)f2bf(v[it][0].z) | ((unsigned)f2bf(v[it][1].z) << 16);
        unsigned d3 = (unsigned)f2bf(v[it][0].w) | ((unsigned)f2bf(v[it][1].w) << 16);
        int rb = (r * 66 + q * 4 + 1) * XSPAD + 2 * icp;
        *(unsigned*)&xb[rb]             = d0;
        *(unsigned*)&xb[rb + XSPAD]     = d1;
        *(unsigned*)&xb[rb + 2 * XSPAD] = d2;
        *(unsigned*)&xb[rb + 3 * XSPAD] = d3;
    }
}

// weights for chunk ck: whs 8192 el, wka (taps 0-3) 8192 el, wkb (taps 4-7) 8192 el.
// All linear copies -> global_load_lds width 16 (wave-uniform LDS base + lane*16).
__device__ __forceinline__ void stage_w_dma(const unsigned short* __restrict__ wgt, int ck, int t,
                                            unsigned short* __restrict__ whs,
                                            unsigned short* __restrict__ wka,
                                            unsigned short* __restrict__ wkb) {
    const unsigned short* AH = wgt + ck * 8192;
    const unsigned short* AK = wgt + 65536 + ck * 16384;
    #pragma unroll
    for (int k = 0; k < 4; ++k) {
        int e = (t + k * 256) * 8;
        __builtin_amdgcn_global_load_lds(
            (const __attribute__((address_space(1))) unsigned int*)&AH[e],
            (__attribute__((address_space(3))) unsigned int*)&whs[e], 16, 0, 0);
        __builtin_amdgcn_global_load_lds(
            (const __attribute__((address_space(1))) unsigned int*)&AK[e],
            (__attribute__((address_space(3))) unsigned int*)&wka[e], 16, 0, 0);
        __builtin_amdgcn_global_load_lds(
            (const __attribute__((address_space(1))) unsigned int*)&AK[8192 + e],
            (__attribute__((address_space(3))) unsigned int*)&wkb[e], 16, 0, 0);
    }
}

__device__ __forceinline__ bf16x8 lds_bfrag(const unsigned short* __restrict__ xb, int off) {
    bf16x4 lo = *(const bf16x4*)&xb[off];
    bf16x4 hi = *(const bf16x4*)&xb[off + 4];
    return __builtin_shufflevector(lo, hi, 0, 1, 2, 3, 4, 5, 6, 7);
}

template <int G>
__device__ __forceinline__ void compute_chunk(const unsigned short* __restrict__ xb,
        const unsigned short* __restrict__ whs,
        const unsigned short* __restrict__ wka,
        const unsigned short* __restrict__ wkb,
        f32x4 acc[8][4], int mrow, int ncol, int lrow, int kc) {
    // ---- part A: dense pointwise, K=32 ----
    bf16x8 bfr[4];
    #pragma unroll
    for (int ni = 0; ni < 4; ++ni)
        bfr[ni] = lds_bfrag(xb, ((ncol + 1) * 66 + ni * 16 + lrow + 1) * XSPAD + kc * 8);
    #pragma unroll
    for (int mi = 0; mi < 8; ++mi) {
        int m = mrow + 2 * mi;
        bf16x8 a = *(const bf16x8*)&whs[(m * 16 + lrow) * 32 + kc * 8];
        #pragma unroll
        for (int ni = 0; ni < 4; ++ni)
            acc[mi][ni] = __builtin_amdgcn_mfma_f32_16x16x32_bf16(a, bfr[ni], acc[mi][ni], 0, 0, 0);
    }
    // ---- part B: 8 non-center taps, group G ----
    #pragma unroll
    for (int tf = 0; tf < 8; ++tf) {
        const int tfull = tf < 4 ? tf : tf + 1;
        const int dy = tfull / 3 - 1, dx = tfull % 3 - 1;
        const unsigned short* wkbuf = (tf < 4) ? wka : wkb;
        const unsigned short* ak = &wkbuf[(((tf & 3) * 64 + mrow * 16 + lrow) * 4 + kc) * 8];
        bf16x8 a0 = *(const bf16x8*)ak;
        bf16x8 a1 = *(const bf16x8*)(ak + 1024);   // rows +32
        #pragma unroll
        for (int ni = 0; ni < 4; ++ni) {
            bf16x8 bb = lds_bfrag(xb, ((ncol + 1 + dy) * 66 + ni * 16 + lrow + 1 + dx) * XSPAD + kc * 8);
            acc[2 * G + 0][ni] = __builtin_amdgcn_mfma_f32_16x16x32_bf16(a0, bb, acc[2 * G + 0][ni], 0, 0, 0);
            acc[2 * G + 1][ni] = __builtin_amdgcn_mfma_f32_16x16x32_bf16(a1, bb, acc[2 * G + 1][ni], 0, 0, 0);
        }
    }
}

// ---------------- main MFMA kernel ----------------
// 256 threads = 4 waves (2 mrow x 2 ncol). Block: 256 oc x 2 output rows x 64 cols.
__global__ __launch_bounds__(256, 2)
void hetconv_mfma(const float* __restrict__ x,
                  const unsigned short* __restrict__ wgt,
                  float* __restrict__ out) {
    __shared__ __align__(16) unsigned short xs[XSSZ];     // 19008 B
    __shared__ __align__(16) unsigned short whs[8192];    // 16384 B
    __shared__ __align__(16) unsigned short wka[8192];    // 16384 B (taps 0-3)
    __shared__ __align__(16) unsigned short wkb[8192];    // 16384 B (taps 4-7)

    const int t    = threadIdx.x;
    const int l    = t & 63;
    const int w    = t >> 6;
    const int mrow = w & 1;
    const int ncol = w >> 1;
    const int lrow = l & 15;
    const int kc   = l >> 4;

    const int bid = blockIdx.x;                 // 1024 blocks
    const int n   = (bid & 7) * 4 + (bid >> 8); // XCD-major n (round-2 proven mapping)
    const int y0  = ((bid >> 3) & 31) * 2;

    f32x4 acc[8][4];
    #pragma unroll
    for (int mi = 0; mi < 8; ++mi)
        #pragma unroll
        for (int ni = 0; ni < 4; ++ni) acc[mi][ni] = (f32x4){0.f, 0.f, 0.f, 0.f};

    // ---- prologue: zero halo cols, stage chunk 0 (x via VGPR, weights via DMA) ----
    {
        float4 xv[4][2];
        stage_x_loads(x, n, y0, 0, t, xv);
        stage_w_dma(wgt, 0, t, whs, wka, wkb);
        if (t < 128) {   // 4 r x 2 side x 16 dwords
            int r = t >> 5, side = (t >> 4) & 1, u = t & 15;
            *(unsigned*)&xs[(r * 66 + side * 65) * XSPAD + u * 2] = 0u;
        }
        stage_x_writes(t, xv, xs);
        __syncthreads();   // drains lgkmcnt (ds_write) and vmcnt (DMA)
    }

    // ---- main loop: 8 chunks, 2 barriers each ----
    #pragma unroll 1
    for (int h2 = 0; h2 < 2; ++h2) {
#define BODY(G)                                                                    \
        {                                                                          \
            const int ck = h2 * 4 + G;                                             \
            float4 xv[4][2];                                                       \
            if (G < 3 || h2 == 0) stage_x_loads(x, n, y0, ck + 1, t, xv);          \
            compute_chunk<G>(xs, whs, wka, wkb, acc, mrow, ncol, lrow, kc);        \
            __syncthreads();                                                       \
            if (G < 3 || h2 == 0) {                                                \
                stage_w_dma(wgt, ck + 1, t, whs, wka, wkb);                        \
                stage_x_writes(t, xv, xs);                                         \
            }                                                                      \
            __syncthreads();                                                       \
        }
        BODY(0) BODY(1) BODY(2) BODY(3)
#undef BODY
    }

    // ---- epilogue: C/D layout col=lane&15, row=(lane>>4)*4+reg ----
    #pragma unroll
    for (int mi = 0; mi < 8; ++mi) {
        int m = mrow + 2 * mi;
        #pragma unroll
        for (int ni = 0; ni < 4; ++ni) {
            #pragma unroll
            for (int reg = 0; reg < 4; ++reg) {
                int p  = m * 16 + kc * 4 + reg;
                int oc = 4 * (p & 63) + (p >> 6);
                out[(((size_t)n * OUT_C + oc) * HH + (y0 + ncol)) * WW + ni * 16 + lrow] = acc[mi][ni][reg];
            }
        }
    }
}

// ---------------- fp32 fallback (only if ws too small) ----------------
#define TH 16
#define TW 16
#define ICC 16
__global__ __launch_bounds__(256)
void hetconv_fp32(const float* __restrict__ x,
                  const float* __restrict__ Wk,
                  const float* __restrict__ W1,
                  float* __restrict__ out) {
    const int t    = threadIdx.x;
    const int g    = blockIdx.y;
    const int n    = blockIdx.z;
    const int tile = blockIdx.x;
    const int ty0  = (tile >> 2) * TH;
    const int tx0  = (tile & 3) * TW;
    const int ol = t & 7;
    const int pl = t >> 3;
    const int r  = pl >> 1;
    const int ch = (pl & 1) * 8;
    __shared__ __align__(16) float xsf[ICC * 18 * 20];
    __shared__ __align__(16) float w1s[ICC * 64];
    __shared__ __align__(16) float wksf[4 * 9 * 64];
    float acc[8][8];
    #pragma unroll
    for (int k = 0; k < 8; ++k)
        #pragma unroll
        for (int p = 0; p < 8; ++p) acc[k][p] = 0.f;
    for (int ic0 = 0; ic0 < IN_C; ic0 += ICC) {
        for (int idx = t; idx < ICC * 18 * 18; idx += 256) {
            int ic = idx / 324, rem = idx - ic * 324, rr = rem / 18, cc = rem - rr * 18;
            int gy = ty0 + rr - 1, gx = tx0 + cc - 1;
            float v = 0.f;
            if (gy >= 0 && gy < HH && gx >= 0 && gx < WW)
                v = x[(((size_t)n * IN_C + ic0 + ic) * HH + gy) * WW + gx];
            xsf[ic * 360 + rr * 20 + cc] = v;
        }
        for (int idx = t; idx < ICC * 64; idx += 256) {
            int ic = idx >> 6, o = idx & 63;
            w1s[idx] = W1[(g + 4 * o) * IN_C + ic0 + ic];
        }
        for (int idx = t; idx < 4 * 9 * 64; idx += 256) {
            int a = idx / 576, rem = idx - a * 576, tap = rem >> 6, o = rem & 63;
            wksf[idx] = Wk[((g + 4 * o) * IN_C + ic0 + g + 4 * a) * 9 + tap];
        }
        __syncthreads();
        for (int ic = 0; ic < ICC; ++ic) {
            if ((ic & 3) != g) {
                const float* rowp = &xsf[ic * 360 + (r + 1) * 20 + ch];
                float4 A = *(const float4*)rowp;
                float4 B = *(const float4*)(rowp + 4);
                float  c8 = rowp[8];
                float xv[8] = {A.y, A.z, A.w, B.x, B.y, B.z, B.w, c8};
                const float* wp = &w1s[ic * 64 + ol * 8];
                float4 wA = *(const float4*)wp;
                float4 wB = *(const float4*)(wp + 4);
                float wv[8] = {wA.x, wA.y, wA.z, wA.w, wB.x, wB.y, wB.z, wB.w};
                #pragma unroll
                for (int k = 0; k < 8; ++k)
                    #pragma unroll
                    for (int p = 0; p < 8; ++p) acc[k][p] += wv[k] * xv[p];
            } else {
                const int a = ic >> 2;
                #pragma unroll
                for (int dy = -1; dy <= 1; ++dy) {
                    const float* rowp = &xsf[ic * 360 + (r + 1 + dy) * 20 + ch];
                    float4 A = *(const float4*)rowp;
                    float4 B = *(const float4*)(rowp + 4);
                    float2 C = *(const float2*)(rowp + 8);
                    float seg[10] = {A.x, A.y, A.z, A.w, B.x, B.y, B.z, B.w, C.x, C.y};
                    #pragma unroll
                    for (int dxi = 0; dxi < 3; ++dxi) {
                        const float* wp = &wksf[(a * 9 + (dy + 1) * 3 + dxi) * 64 + ol * 8];
                        float4 wA = *(const float4*)wp;
                        float4 wB = *(const float4*)(wp + 4);
                        float wv[8] = {wA.x, wA.y, wA.z, wA.w, wB.x, wB.y, wB.z, wB.w};
                        #pragma unroll
                        for (int k = 0; k < 8; ++k)
                            #pragma unroll
                            for (int p = 0; p < 8; ++p) acc[k][p] += wv[k] * seg[p + dxi];
                    }
                }
            }
        }
        __syncthreads();
    }
    #pragma unroll
    for (int k = 0; k < 8; ++k) {
        int oc = g + 4 * (ol * 8 + k);
        size_t base = (((size_t)n * OUT_C + oc) * HH + (ty0 + r)) * WW + tx0 + ch;
        float4 v0 = {acc[k][0], acc[k][1], acc[k][2], acc[k][3]};
        float4 v1 = {acc[k][4], acc[k][5], acc[k][6], acc[k][7]};
        *(float4*)(&out[base])     = v0;
        *(float4*)(&out[base + 4]) = v1;
    }
}

extern "C" void kernel_launch(void* const* d_in, const int* in_sizes, int n_in,
                              void* d_out, int out_size, void* d_ws, size_t ws_size,
                              hipStream_t stream) {
    const float* x  = (const float*)d_in[0];
    const float* Wk = (const float*)d_in[1];
    const float* W1 = (const float*)d_in[2];
    float* outp = (float*)d_out;

    if (ws_size >= (size_t)(65536 + 131072) * sizeof(unsigned short)) {
        hetconv_prep<<<256, 256, 0, stream>>>(Wk, W1, (unsigned short*)d_ws);
        hetconv_mfma<<<1024, 256, 0, stream>>>(x, (const unsigned short*)d_ws, outp);
    } else {
        hetconv_fp32<<<dim3(16, 4, 32), 256, 0, stream>>>(x, Wk, W1, outp);
    }
}

// Round 7
// 118.461 us; speedup vs baseline: 1.6867x; 1.4632x over previous
//
#include <hip/hip_runtime.h>

// HetConv via bf16 MFMA implicit GEMM, v7.
// M=128 per block (mh half), N=128 px (2 rows x 64). K visited in order
// [0,2,1,3,4,6,5,7] so part-B-active chunks alternate with inactive ones for
// both mh values -> wk DMA only ever issued while nobody reads it (race-free,
// no wk double-buffer). whs ping-pong; xs single-buffered. All global loads /
// DMAs issued at chunk top, compute covers latency, 2 barriers per chunk.
// LDS 80448 B -> 2 blocks/CU.

#define IN_C  256
#define OUT_C 256
#define HH    64
#define WW    64

typedef __attribute__((ext_vector_type(8))) short bf16x8;
typedef __attribute__((ext_vector_type(4))) short bf16x4;
typedef __attribute__((ext_vector_type(4))) float f32x4;

__device__ __forceinline__ unsigned short f2bf(float f) {
    union { float f; unsigned int u; } v; v.f = f;
    unsigned int r = (v.u + 0x7FFFu + ((v.u >> 16) & 1u)) >> 16;
    return (unsigned short)r;
}

// ---------------- weight prepass ----------------
// WH: [mh(2)][ck(8)][pr(128)][40]                    = 81920 elems
// WK: offset 81920: [ck(8)][half(2)][tap(4)][lo(64)][40] = 163840 elems
//   g = ck&3, h2 = ck>>2 ; j = g + 4*(32*h2 + i) ; tf = half*4+tap ;
//   tfull = tf<4 ? tf : tf+1 ; rows pad-40 (zeros in i>=32) for aligned,
//   bank-conflict-free b128 fragment reads.
__global__ __launch_bounds__(256)
void hetconv_prep(const float* __restrict__ Wk, const float* __restrict__ W1,
                  unsigned short* __restrict__ ws16) {
    const int TOTAL = 81920 + 163840;
    for (int idx = blockIdx.x * 256 + threadIdx.x; idx < TOTAL; idx += gridDim.x * 256) {
        float f = 0.f;
        if (idx < 81920) {
            int i40 = idx % 40;
            int rem = idx / 40;          // 0..2047
            int pr  = rem & 127;
            int ck  = (rem >> 7) & 7;
            int mh  = rem >> 10;
            if (i40 < 32) {
                int g = ck & 3, h2 = ck >> 2;
                int j = g + 4 * (32 * h2 + i40);
                int p = 128 * mh + pr;
                int oc = 4 * (p & 63) + (p >> 6);
                f = ((p >> 6) == g) ? Wk[(oc * IN_C + j) * 9 + 4] : W1[oc * IN_C + j];
            }
        } else {
            int k   = idx - 81920;
            int i40 = k % 40;
            int rem = k / 40;            // 0..4095
            int lo  = rem & 63;
            int tap = (rem >> 6) & 3;
            int hf  = (rem >> 8) & 1;
            int ck  = rem >> 9;
            if (i40 < 32) {
                int g = ck & 3, h2 = ck >> 2;
                int tf = hf * 4 + tap;
                int tfull = tf < 4 ? tf : tf + 1;
                int oc = 4 * lo + g;
                int j  = g + 4 * (32 * h2 + i40);
                f = Wk[(oc * IN_C + j) * 9 + tfull];
            }
        }
        ws16[idx] = f2bf(f);
    }
}

// ---------------- main kernel helpers ----------------
#define XSPAD 36
#define XSSZ  (4 * 66 * XSPAD)   // 9504 elems (19008 B)

// x chunk: 32 ic x 4 rows x 64 cols. tasks [r(4)][q(16)][icp(16)] = 1024 = 256*4
__device__ __forceinline__ void stage_x_loads(const float* __restrict__ x, int n, int y0,
                                              int ck, int t, float4 v[4][2]) {
    const int g = ck & 3, h2 = ck >> 2;
    #pragma unroll
    for (int it = 0; it < 4; ++it) {
        int tau = t + it * 256;
        int icp = tau & 15, q = (tau >> 4) & 15, r = tau >> 8;
        int j0 = g + 4 * (32 * h2 + 2 * icp);
        int gy = y0 + r - 1;
        float4 z = {0.f, 0.f, 0.f, 0.f};
        v[it][0] = z; v[it][1] = z;
        if ((unsigned)gy < 64u) {
            const float* p0 = x + (((size_t)n * IN_C + j0) << 12) + (gy << 6) + (q << 2);
            v[it][0] = *(const float4*)p0;
            v[it][1] = *(const float4*)(p0 + 16384);   // plane j0+4
        }
    }
}

__device__ __forceinline__ void stage_x_writes(int t, float4 v[4][2], unsigned short* __restrict__ xb) {
    #pragma unroll
    for (int it = 0; it < 4; ++it) {
        int tau = t + it * 256;
        int icp = tau & 15, q = (tau >> 4) & 15, r = tau >> 8;
        unsigned d0 = (unsigned)f2bf(v[it][0].x) | ((unsigned)f2bf(v[it][1].x) << 16);
        unsigned d1 = (unsigned)f2bf(v[it][0].y) | ((unsigned)f2bf(v[it][1].y) << 16);
        unsigned d2 = (unsigned)f2bf(v[it][0].z) | ((unsigned)f2bf(v[it][1].z) << 16);
        unsigned d3 = (unsigned)f2bf(v[it][0].w) | ((unsigned)f2bf(v[it][1].w) << 16);
        int rb = (r * 66 + q * 4 + 1) * XSPAD + 2 * icp;
        *(unsigned*)&xb[rb]             = d0;
        *(unsigned*)&xb[rb + XSPAD]     = d1;
        *(unsigned*)&xb[rb + 2 * XSPAD] = d2;
        *(unsigned*)&xb[rb + 3 * XSPAD] = d3;
    }
}

// --- weight DMA (global_load_lds width 16; prepack layout == LDS layout, linear) ---
__device__ __forceinline__ void dma_wh(const unsigned short* __restrict__ wgt,
                                       int mh, int ck, int t, unsigned short* __restrict__ dst) {
    const unsigned short* src = wgt + (mh * 8 + ck) * 5120;   // 5120 el = 10240 B = 640 x16B
    #pragma unroll
    for (int k = 0; k < 3; ++k) {
        int idx = t + k * 256;
        if (idx < 640)
            __builtin_amdgcn_global_load_lds(
                (const __attribute__((address_space(1))) unsigned int*)&src[idx * 8],
                (__attribute__((address_space(3))) unsigned int*)&dst[idx * 8], 16, 0, 0);
    }
}

__device__ __forceinline__ void dma_wk_half(const unsigned short* __restrict__ wgt,
                                            int ck, int half, int t, unsigned short* __restrict__ dst) {
    const unsigned short* src = wgt + 81920 + (ck * 2 + half) * 10240;  // 20480 B = 1280 x16B
    #pragma unroll
    for (int k = 0; k < 5; ++k) {
        int idx = t + k * 256;
        __builtin_amdgcn_global_load_lds(
            (const __attribute__((address_space(1))) unsigned int*)&src[idx * 8],
            (__attribute__((address_space(3))) unsigned int*)&dst[idx * 8], 16, 0, 0);
    }
}

__device__ __forceinline__ bf16x8 lds_bfrag(const unsigned short* __restrict__ xb, int off) {
    bf16x4 lo = *(const bf16x4*)&xb[off];
    bf16x4 hi = *(const bf16x4*)&xb[off + 4];
    return __builtin_shufflevector(lo, hi, 0, 1, 2, 3, 4, 5, 6, 7);
}

// Part A: dense pointwise for this M-half. 16 MFMA per wave.
__device__ __forceinline__ void compute_A(const unsigned short* __restrict__ xb,
        const unsigned short* __restrict__ wh, f32x4 acc[4][4],
        int mrow, int ncol, int lrow, int kc) {
    bf16x8 bfr[4];
    #pragma unroll
    for (int ni = 0; ni < 4; ++ni)
        bfr[ni] = lds_bfrag(xb, ((ncol + 1) * 66 + ni * 16 + lrow + 1) * XSPAD + kc * 8);
    #pragma unroll
    for (int mi = 0; mi < 4; ++mi) {
        int mt = mrow + 2 * mi;
        bf16x8 a = *(const bf16x8*)&wh[(mt * 16 + lrow) * 40 + kc * 8];
        #pragma unroll
        for (int ni = 0; ni < 4; ++ni)
            acc[mi][ni] = __builtin_amdgcn_mfma_f32_16x16x32_bf16(a, bfr[ni], acc[mi][ni], 0, 0, 0);
    }
}

// Part B tap-half: 4 taps x 2 m-tiles x 4 ni = 32 MFMA per wave. G1 = ck&1.
template <int G1, int HALF>
__device__ __forceinline__ void compute_taps(const unsigned short* __restrict__ xb,
        const unsigned short* __restrict__ wkh, f32x4 acc[4][4],
        int mrow, int ncol, int lrow, int kc) {
    #pragma unroll
    for (int tp = 0; tp < 4; ++tp) {
        const int tf = HALF * 4 + tp;
        const int tfull = tf < 4 ? tf : tf + 1;
        const int dy = tfull / 3 - 1, dx = tfull % 3 - 1;
        const unsigned short* ak = &wkh[(tp * 64 + mrow * 16 + lrow) * 40 + kc * 8];
        bf16x8 a0 = *(const bf16x8*)ak;
        bf16x8 a1 = *(const bf16x8*)(ak + 1280);   // +32 lo rows
        #pragma unroll
        for (int ni = 0; ni < 4; ++ni) {
            bf16x8 bb = lds_bfrag(xb, ((ncol + 1 + dy) * 66 + ni * 16 + lrow + 1 + dx) * XSPAD + kc * 8);
            acc[2 * G1 + 0][ni] = __builtin_amdgcn_mfma_f32_16x16x32_bf16(a0, bb, acc[2 * G1 + 0][ni], 0, 0, 0);
            acc[2 * G1 + 1][ni] = __builtin_amdgcn_mfma_f32_16x16x32_bf16(a1, bb, acc[2 * G1 + 1][ni], 0, 0, 0);
        }
    }
}

// ---------------- main MFMA kernel ----------------
// 256 thr = 4 waves (mrow = w&1, ncol = w>>1). Block: M=128 p-rows x 2 out rows x 64 cols.
__global__ __launch_bounds__(256, 2)
void hetconv_mfma(const float* __restrict__ x,
                  const unsigned short* __restrict__ wgt,
                  float* __restrict__ out) {
    __shared__ __align__(16) unsigned short xs[XSSZ];        // 19008 B
    __shared__ __align__(16) unsigned short whs[2][5120];    // 20480 B (ping-pong)
    __shared__ __align__(16) unsigned short wk[2][10240];    // 40960 B (taps 0-3 / 4-7)
                                                             // total 80448 B -> 2 blocks/CU
    const int t    = threadIdx.x;
    const int l    = t & 63;
    const int w    = t >> 6;
    const int mrow = w & 1;
    const int ncol = w >> 1;
    const int lrow = l & 15;
    const int kc   = l >> 4;

    // bid: xcd = bid&7; q = bid>>3: mh = q&1 (mh-pair adjacent -> same XCD, shared x
    // in L2), y0 = ((q>>1)&31)*2, n = xcd*4 + (q>>6).
    const int bid = blockIdx.x;
    const int q   = bid >> 3;
    const int mh  = q & 1;
    const int y0  = ((q >> 1) & 31) * 2;
    const int n   = (bid & 7) * 4 + (q >> 6);

    f32x4 acc[4][4];
    #pragma unroll
    for (int mi = 0; mi < 4; ++mi)
        #pragma unroll
        for (int ni = 0; ni < 4; ++ni) acc[mi][ni] = (f32x4){0.f, 0.f, 0.f, 0.f};

    // ---- prologue: stage chunk 0 (+ wk iff chunk 0 is active, i.e. mh==0) ----
    {
        float4 xv[4][2];
        stage_x_loads(x, n, y0, 0, t, xv);
        dma_wh(wgt, mh, 0, t, whs[0]);
        if (mh == 0) { dma_wk_half(wgt, 0, 0, t, wk[0]); dma_wk_half(wgt, 0, 1, t, wk[1]); }
        if (t < 128) {   // zero halo cols (0, 65) of 4 rows: 4r x 2side x 16 dwords
            int r = t >> 5, side = (t >> 4) & 1, u = t & 15;
            *(unsigned*)&xs[(r * 66 + side * 65) * XSPAD + u * 2] = 0u;
        }
        stage_x_writes(t, xv, xs);
        __syncthreads();   // drains ds_writes + all DMA (vmcnt0)
    }

    // ---- 8 positions; K-chunk order {0,2,1,3,4,6,5,7} alternates part-B activity ----
    // Top of position S: issue x loads + wh DMA (into idle ping buffer) + wk DMA
    // (only when NEXT chunk is active => CURRENT chunk never reads wk => no race).
#define POS(S, CK, NXT, LAST)                                                     \
    {                                                                             \
        const bool actc = (((CK) >> 1) & 1) == mh;                                \
        const bool actn = (((NXT) >> 1) & 1) == mh;                               \
        float4 xv[4][2];                                                          \
        if (!(LAST)) {                                                            \
            stage_x_loads(x, n, y0, (NXT), t, xv);                                \
            dma_wh(wgt, mh, (NXT), t, whs[((S) + 1) & 1]);                        \
            if (actn) {                                                           \
                dma_wk_half(wgt, (NXT), 0, t, wk[0]);                             \
                dma_wk_half(wgt, (NXT), 1, t, wk[1]);                             \
            }                                                                     \
        }                                                                         \
        compute_A(xs, whs[(S) & 1], acc, mrow, ncol, lrow, kc);                   \
        if (actc) {                                                               \
            compute_taps<(CK) & 1, 0>(xs, wk[0], acc, mrow, ncol, lrow, kc);      \
            compute_taps<(CK) & 1, 1>(xs, wk[1], acc, mrow, ncol, lrow, kc);      \
        }                                                                         \
        __syncthreads();                /* all reads of xs/whs/wk done */         \
        if (!(LAST)) stage_x_writes(t, xv, xs);                                   \
        __syncthreads();                /* xs visible; DMAs drained */            \
    }

    POS(0, 0, 2, 0) POS(1, 2, 1, 0) POS(2, 1, 3, 0) POS(3, 3, 4, 0)
    POS(4, 4, 6, 0) POS(5, 6, 5, 0) POS(6, 5, 7, 0) POS(7, 7, 0, 1)
#undef POS

    // ---- epilogue: C/D layout col=lane&15, row=(lane>>4)*4+reg ----
    #pragma unroll
    for (int mi = 0; mi < 4; ++mi) {
        int mt = mrow + 2 * mi;
        #pragma unroll
        for (int ni = 0; ni < 4; ++ni) {
            #pragma unroll
            for (int reg = 0; reg < 4; ++reg) {
                int p  = 128 * mh + mt * 16 + kc * 4 + reg;
                int oc = 4 * (p & 63) + (p >> 6);
                out[(((size_t)n * OUT_C + oc) * HH + (y0 + ncol)) * WW + ni * 16 + lrow] = acc[mi][ni][reg];
            }
        }
    }
}

// ---------------- fp32 fallback (only if ws too small) ----------------
#define TH 16
#define TW 16
#define ICC 16
__global__ __launch_bounds__(256)
void hetconv_fp32(const float* __restrict__ x,
                  const float* __restrict__ Wk,
                  const float* __restrict__ W1,
                  float* __restrict__ out) {
    const int t    = threadIdx.x;
    const int g    = blockIdx.y;
    const int n    = blockIdx.z;
    const int tile = blockIdx.x;
    const int ty0  = (tile >> 2) * TH;
    const int tx0  = (tile & 3) * TW;
    const int ol = t & 7;
    const int pl = t >> 3;
    const int r  = pl >> 1;
    const int ch = (pl & 1) * 8;
    __shared__ __align__(16) float xsf[ICC * 18 * 20];
    __shared__ __align__(16) float w1s[ICC * 64];
    __shared__ __align__(16) float wksf[4 * 9 * 64];
    float acc[8][8];
    #pragma unroll
    for (int k = 0; k < 8; ++k)
        #pragma unroll
        for (int p = 0; p < 8; ++p) acc[k][p] = 0.f;
    for (int ic0 = 0; ic0 < IN_C; ic0 += ICC) {
        for (int idx = t; idx < ICC * 18 * 18; idx += 256) {
            int ic = idx / 324, rem = idx - ic * 324, rr = rem / 18, cc = rem - rr * 18;
            int gy = ty0 + rr - 1, gx = tx0 + cc - 1;
            float v = 0.f;
            if (gy >= 0 && gy < HH && gx >= 0 && gx < WW)
                v = x[(((size_t)n * IN_C + ic0 + ic) * HH + gy) * WW + gx];
            xsf[ic * 360 + rr * 20 + cc] = v;
        }
        for (int idx = t; idx < ICC * 64; idx += 256) {
            int ic = idx >> 6, o = idx & 63;
            w1s[idx] = W1[(g + 4 * o) * IN_C + ic0 + ic];
        }
        for (int idx = t; idx < 4 * 9 * 64; idx += 256) {
            int a = idx / 576, rem = idx - a * 576, tap = rem >> 6, o = rem & 63;
            wksf[idx] = Wk[((g + 4 * o) * IN_C + ic0 + g + 4 * a) * 9 + tap];
        }
        __syncthreads();
        for (int ic = 0; ic < ICC; ++ic) {
            if ((ic & 3) != g) {
                const float* rowp = &xsf[ic * 360 + (r + 1) * 20 + ch];
                float4 A = *(const float4*)rowp;
                float4 B = *(const float4*)(rowp + 4);
                float  c8 = rowp[8];
                float xv[8] = {A.y, A.z, A.w, B.x, B.y, B.z, B.w, c8};
                const float* wp = &w1s[ic * 64 + ol * 8];
                float4 wA = *(const float4*)wp;
                float4 wB = *(const float4*)(wp + 4);
                float wv[8] = {wA.x, wA.y, wA.z, wA.w, wB.x, wB.y, wB.z, wB.w};
                #pragma unroll
                for (int k = 0; k < 8; ++k)
                    #pragma unroll
                    for (int p = 0; p < 8; ++p) acc[k][p] += wv[k] * xv[p];
            } else {
                const int a = ic >> 2;
                #pragma unroll
                for (int dy = -1; dy <= 1; ++dy) {
                    const float* rowp = &xsf[ic * 360 + (r + 1 + dy) * 20 + ch];
                    float4 A = *(const float4*)rowp;
                    float4 B = *(const float4*)(rowp + 4);
                    float2 C = *(const float2*)(rowp + 8);
                    float seg[10] = {A.x, A.y, A.z, A.w, B.x, B.y, B.z, B.w, C.x, C.y};
                    #pragma unroll
                    for (int dxi = 0; dxi < 3; ++dxi) {
                        const float* wp = &wksf[(a * 9 + (dy + 1) * 3 + dxi) * 64 + ol * 8];
                        float4 wA = *(const float4*)wp;
                        float4 wB = *(const float4*)(wp + 4);
                        float wv[8] = {wA.x, wA.y, wA.z, wA.w, wB.x, wB.y, wB.z, wB.w};
                        #pragma unroll
                        for (int k = 0; k < 8; ++k)
                            #pragma unroll
                            for (int p = 0; p < 8; ++p) acc[k][p] += wv[k] * seg[p + dxi];
                    }
                }
            }
        }
        __syncthreads();
    }
    #pragma unroll
    for (int k = 0; k < 8; ++k) {
        int oc = g + 4 * (ol * 8 + k);
        size_t base = (((size_t)n * OUT_C + oc) * HH + (ty0 + r)) * WW + tx0 + ch;
        float4 v0 = {acc[k][0], acc[k][1], acc[k][2], acc[k][3]};
        float4 v1 = {acc[k][4], acc[k][5], acc[k][6], acc[k][7]};
        *(float4*)(&out[base])     = v0;
        *(float4*)(&out[base + 4]) = v1;
    }
}

extern "C" void kernel_launch(void* const* d_in, const int* in_sizes, int n_in,
                              void* d_out, int out_size, void* d_ws, size_t ws_size,
                              hipStream_t stream) {
    const float* x  = (const float*)d_in[0];
    const float* Wk = (const float*)d_in[1];
    const float* W1 = (const float*)d_in[2];
    float* outp = (float*)d_out;

    if (ws_size >= (size_t)(81920 + 163840) * sizeof(unsigned short)) {
        hetconv_prep<<<240, 256, 0, stream>>>(Wk, W1, (unsigned short*)d_ws);
        hetconv_mfma<<<2048, 256, 0, stream>>>(x, (const unsigned short*)d_ws, outp);
    } else {
        hetconv_fp32<<<dim3(16, 4, 32), 256, 0, stream>>>(x, Wk, W1, outp);
    }
}